// Round 4
// baseline (524.866 us; speedup 1.0000x reference)
//
#include <hip/hip_runtime.h>
#include <hip/hip_bf16.h>
#include <cstdint>
#include <cstddef>

typedef __hip_bfloat16 bf16;

#define N_NODES  50000
#define N_EDGES  150000
#define N_GRAPHS 1024
#define IN_DIM   78
#define K1P      128                   /* IN_DIM padded to mult of 64 (BK) */
#define OUT_DIM  64
#define HEADS    10
#define HID      640
#define NEG_SLOPE 0.2f
#define SCB      ((N_NODES + 255) / 256)   /* 196 scan blocks */

static __device__ __forceinline__ float b2f(bf16 v){ return __bfloat162float(v); }
static __device__ __forceinline__ bf16  f2b(float v){ return __float2bfloat16(v); }

__device__ __forceinline__ int clampi(int v, int hi){ return v < 0 ? 0 : (v >= hi ? hi - 1 : v); }

__device__ __forceinline__ float bf2f_bits(short s){
  return __uint_as_float(((unsigned)(unsigned short)s) << 16);
}
__device__ __forceinline__ short f2bf_bits(float v){      // RNE (used where accuracy matters)
  unsigned u = __float_as_uint(v);
  return (short)((u + 0x7fffu + ((u >> 16) & 1u)) >> 16);
}

// ---------------------------------------------------------------- fills
__global__ __launch_bounds__(256) void fill_u32(unsigned* __restrict__ p, unsigned v, int n){
  int i = blockIdx.x * 256 + threadIdx.x;
  if (i < n) p[i] = v;
}

// ---------------------------------------------------------------- dtype prep
__global__ __launch_bounds__(256) void conv_x(const float* __restrict__ x, bf16* __restrict__ XB){
  int i = blockIdx.x * 256 + threadIdx.x;
  if (i >= N_NODES * K1P) return;
  int n = i / K1P, k = i - n * K1P;
  XB[i] = f2b(k < IN_DIM ? x[(size_t)n * IN_DIM + k] : 0.f);
}

// 2 weight matrices -> contiguous transposed bf16 (layer-1 pair, K padded; small)
__global__ __launch_bounds__(256) void conv_wT2(const float* __restrict__ W0,
                                                const float* __restrict__ W1,
                                                bf16* __restrict__ WT,
                                                int K, int N, int Kp){
  int i = blockIdx.x * 256 + threadIdx.x;
  const int per = N * Kp;
  if (i >= 2 * per) return;
  int m = i / per, r = i - m * per;
  const float* W = m == 0 ? W0 : W1;
  int n = r / Kp, k = r - n * Kp;
  WT[i] = f2b(k < K ? W[(size_t)k * N + n] : 0.f);
}

// tiled transpose: 3x (640x640 f32, row-major k x n) -> bf16 WT[m][n][k]
__global__ __launch_bounds__(256) void conv_wT3t(const float* __restrict__ W0,
                                                 const float* __restrict__ W1,
                                                 const float* __restrict__ W2,
                                                 bf16* __restrict__ WT){
  __shared__ float t[32][33];
  int m = blockIdx.z;
  const float* W = m == 0 ? W0 : (m == 1 ? W1 : W2);
  int n0 = blockIdx.x * 32, k0 = blockIdx.y * 32;
  int tx = threadIdx.x & 31, ty = threadIdx.x >> 5;   // 32 x 8
#pragma unroll
  for (int r = 0; r < 32; r += 8)
    t[ty + r][tx] = W[(size_t)(k0 + ty + r) * HID + n0 + tx];   // coalesced in n
  __syncthreads();
  bf16* O = WT + (size_t)m * HID * HID;
#pragma unroll
  for (int r = 0; r < 32; r += 8)
    O[(size_t)(n0 + ty + r) * HID + k0 + tx] = f2b(t[tx][ty + r]);  // coalesced in k
}

// ---------------------------------------------------------------- MFMA GEMM (128x128, BK=64) — layer-1 (shallow K)
#define BM 128
#define BN 128
#define BK 64

typedef __attribute__((ext_vector_type(8))) short bf16x8;
typedef __attribute__((ext_vector_type(4))) float f32x4;

typedef const __attribute__((address_space(1))) unsigned gu32;
typedef __attribute__((address_space(3))) unsigned lu32;

__global__ __launch_bounds__(256) void mfma_gemm(const bf16* __restrict__ A,
                                                 const bf16* __restrict__ BT,
                                                 bf16* __restrict__ C0,
                                                 bf16* __restrict__ C1,
                                                 int M, int Kp, int NB){
  // block swizzle: all NB col-tiles of a row strip stay on one XCD (d%8 = XCD round-robin)
  int d   = blockIdx.x;
  int xcd = d & 7, j = d >> 3;
  int cb  = j % NB, ri = j / NB;
  int rb  = ri * 8 + xcd;
  const int row0 = rb * BM;
  if (row0 >= M) return;
  const int col0 = cb * BN;

  // LDS slot (r, kc) holds source k-chunk kc ^ (r&7): full 32-bank coverage, 2-way (free)
  __shared__ short As[BM * BK];   // 16 KB
  __shared__ short Bs[BN * BK];   // 16 KB
  const int tid  = threadIdx.x;
  const int lane = tid & 63;
  const int wave = tid >> 6;
  const int wr   = (wave >> 1) * 64;
  const int wc   = (wave & 1) * 64;
  const int l15  = lane & 15;
  const int quad = lane >> 4;
  const int sw   = l15 & 7;       // row-XOR term (wr, i*16 are multiples of 8)

  const bf16* aptr[4];
  const bf16* bptr[4];
  lu32* lda[4];
  lu32* ldb[4];
#pragma unroll
  for (int t = 0; t < 4; ++t){
    int ci = (t * 4 + wave) * 64 + lane;
    int r  = ci >> 3;
    int sc = (ci & 7) ^ (r & 7);
    int gr = row0 + r; if (gr >= M) gr = M - 1;
    aptr[t] = A  + (size_t)gr * Kp + sc * 8;
    bptr[t] = BT + (size_t)(col0 + r) * Kp + sc * 8;
    lda[t]  = (lu32*)(&As[(t * 4 + wave) * 512]);
    ldb[t]  = (lu32*)(&Bs[(t * 4 + wave) * 512]);
  }

  f32x4 acc[4][4];
#pragma unroll
  for (int i = 0; i < 4; ++i)
#pragma unroll
    for (int jj = 0; jj < 4; ++jj) acc[i][jj] = (f32x4){0.f, 0.f, 0.f, 0.f};

  for (int k0 = 0; k0 < Kp; k0 += BK){
#pragma unroll
    for (int t = 0; t < 4; ++t){
      __builtin_amdgcn_global_load_lds((gu32*)(aptr[t] + k0), lda[t], 16, 0, 0);
      __builtin_amdgcn_global_load_lds((gu32*)(bptr[t] + k0), ldb[t], 16, 0, 0);
    }
    __syncthreads();

#pragma unroll
    for (int ks = 0; ks < 2; ++ks){
      const int slotA = ((ks * 4 + quad) ^ sw) * 8;
      bf16x8 af[4], bfr[4];
#pragma unroll
      for (int i = 0; i < 4; ++i)
        af[i] = *(bf16x8*)(&As[(wr + i * 16 + l15) * BK + slotA]);
#pragma unroll
      for (int jj = 0; jj < 4; ++jj)
        bfr[jj] = *(bf16x8*)(&Bs[(wc + jj * 16 + l15) * BK + slotA]);
#pragma unroll
      for (int i = 0; i < 4; ++i)
#pragma unroll
        for (int jj = 0; jj < 4; ++jj)
          acc[i][jj] = __builtin_amdgcn_mfma_f32_16x16x32_bf16(af[i], bfr[jj], acc[i][jj], 0, 0, 0);
    }
    __syncthreads();
  }

  // epilogue: C/D layout col=lane&15, row=quad*4+reg; column-split dual output
  if (row0 + BM <= M){          // full strip: no row guards
#pragma unroll
    for (int i = 0; i < 4; ++i){
#pragma unroll
      for (int jj = 0; jj < 4; ++jj){
        int gc = col0 + wc + jj * 16 + l15;
        bf16* Cp = (gc < HID) ? C0 : C1;
        size_t cc = (gc < HID) ? gc : gc - HID;
        size_t base = (size_t)(row0 + wr + i * 16 + quad * 4) * HID + cc;
#pragma unroll
        for (int r = 0; r < 4; ++r)
          Cp[base + (size_t)r * HID] = f2b(acc[i][jj][r]);
      }
    }
  } else {
#pragma unroll
    for (int i = 0; i < 4; ++i){
#pragma unroll
      for (int jj = 0; jj < 4; ++jj){
        int gc = col0 + wc + jj * 16 + l15;
        bf16* Cp = (gc < HID) ? C0 : C1;
        int cc   = (gc < HID) ? gc : gc - HID;
#pragma unroll
        for (int r = 0; r < 4; ++r){
          int gr = row0 + wr + i * 16 + quad * 4 + r;
          if (gr < M) Cp[(size_t)gr * HID + cc] = f2b(acc[i][jj][r]);
        }
      }
    }
  }
}

// ---------------------------------------------------------------- MFMA GEMM2 (256x256, BK=32, 4-deep LDS ring,
// 8-phase-style schedule: per K-step 2 phases, each {stage half ∥ ds_read subtile -> s_barrier ->
// lgkmcnt(0) -> setprio(1) 16xMFMA setprio(0) -> s_barrier}; counted vmcnt (8->4->0) at step end only.
// 512 threads = 8 waves (2 wave-rows x 4 wave-cols). Requires Kp % 32 == 0, Kp/32 >= 4 (Kp=640 -> KT=20).
// Swizzle: LDS slot (r, s) holds global k-chunk s ^ ((r>>1)&3); staging source inverse-permuted per-lane
// global addr (LDS dest linear); reads apply same involution. 2-way banks (free).
#define BM2 256
#define BN2 256

__global__ __launch_bounds__(512) void mfma_gemm2(const bf16* __restrict__ A,
                                                  const bf16* __restrict__ BT,
                                                  bf16* __restrict__ C0,
                                                  bf16* __restrict__ C1,
                                                  int M, int Ntot, int Kp, int NB){
  int d   = blockIdx.x;
  int xcd = d & 7, j = d >> 3;
  int cb  = j % NB, ri = j / NB;
  int rb  = ri * 8 + xcd;
  const int row0 = rb * BM2;
  if (row0 >= M) return;
  const int col0 = cb * BN2;

  __shared__ short LDS[4 * 16384];   // 128 KB: 4 ring bufs x (A 256x32 | B 256x32)
  const int tid  = threadIdx.x;
  const int lane = tid & 63;
  const int wave = tid >> 6;
  const int l15  = lane & 15;
  const int quad = lane >> 4;
  const int wr   = (wave >> 2) * 128;   // wave-row: 0 / 128
  const int wc   = (wave & 3) * 64;     // wave-col: 0/64/128/192

  const int KT = Kp / 32;

  // ---- staging setup: per tile, each wave issues 4 global_load_lds (A lo/hi, B lo/hi), 1 KB each ----
  const int rs0 = wave * 16 + (lane >> 2);
  const int rs1 = rs0 + 128;
  const int sl  = lane & 3;
  const int c0  = sl ^ ((rs0 >> 1) & 3);
  const int c1  = sl ^ ((rs1 >> 1) & 3);
  int grA0 = row0 + rs0; if (grA0 >= M)    grA0 = M - 1;
  int grA1 = row0 + rs1; if (grA1 >= M)    grA1 = M - 1;
  int gcB0 = col0 + rs0; if (gcB0 >= Ntot) gcB0 = Ntot - 1;
  int gcB1 = col0 + rs1; if (gcB1 >= Ntot) gcB1 = Ntot - 1;
  const bf16* gA0 = A  + (size_t)grA0 * Kp + c0 * 8;
  const bf16* gA1 = A  + (size_t)grA1 * Kp + c1 * 8;
  const bf16* gB0 = BT + (size_t)gcB0 * Kp + c0 * 8;
  const bf16* gB1 = BT + (size_t)gcB1 * Kp + c1 * 8;
  const int ldsA0 = wave * 512;           // shorts, within buffer
  const int ldsA1 = 4096 + wave * 512;
  const int ldsB0 = 8192 + wave * 512;
  const int ldsB1 = 12288 + wave * 512;

  auto stageA = [&](int t){
    const int bb = (t & 3) * 16384;
    const int k0 = t * 32;
    __builtin_amdgcn_global_load_lds((gu32*)(gA0 + k0), (lu32*)(&LDS[bb + ldsA0]), 16, 0, 0);
    __builtin_amdgcn_global_load_lds((gu32*)(gA1 + k0), (lu32*)(&LDS[bb + ldsA1]), 16, 0, 0);
  };
  auto stageB = [&](int t){
    const int bb = (t & 3) * 16384;
    const int k0 = t * 32;
    __builtin_amdgcn_global_load_lds((gu32*)(gB0 + k0), (lu32*)(&LDS[bb + ldsB0]), 16, 0, 0);
    __builtin_amdgcn_global_load_lds((gu32*)(gB1 + k0), (lu32*)(&LDS[bb + ldsB1]), 16, 0, 0);
  };

  // ---- read offsets (shorts, constant per thread): frag row r, chunk quad, slot quad^((r>>1)&3) ----
  int aoff[8], boff[4];
#pragma unroll
  for (int i = 0; i < 8; ++i){
    int r = wr + i * 16 + l15;
    aoff[i] = r * 32 + (quad ^ ((r >> 1) & 3)) * 8;
  }
#pragma unroll
  for (int jj = 0; jj < 4; ++jj){
    int r = wc + jj * 16 + l15;
    boff[jj] = 8192 + r * 32 + (quad ^ ((r >> 1) & 3)) * 8;
  }

  f32x4 acc[8][4];
#pragma unroll
  for (int i = 0; i < 8; ++i)
#pragma unroll
    for (int jj = 0; jj < 4; ++jj) acc[i][jj] = (f32x4){0.f, 0.f, 0.f, 0.f};

  // ---- prologue: 3 tiles in flight (12 loads), wait tile0 only (counted) ----
  stageA(0); stageB(0); stageA(1); stageB(1); stageA(2); stageB(2);
  asm volatile("s_waitcnt vmcnt(8)" ::: "memory");
  __builtin_amdgcn_s_barrier();
  __builtin_amdgcn_sched_barrier(0);

  for (int k = 0; k < KT; ++k){
    const int bb = (k & 3) * 16384;
    const bool pf = (k + 3 < KT);

    // ---------- phase A: stage A-half of tile k+3 ∥ ds_read B-frags + A-lo; MFMA acc[0..3] ----------
    if (pf) stageA(k + 3);    // target buffer's last reader was step k-1 (behind barrier)
    bf16x8 bfr[4];
#pragma unroll
    for (int jj = 0; jj < 4; ++jj) bfr[jj] = *(bf16x8*)(&LDS[bb + boff[jj]]);
    bf16x8 af[4];
#pragma unroll
    for (int i = 0; i < 4; ++i) af[i] = *(bf16x8*)(&LDS[bb + aoff[i]]);
    __builtin_amdgcn_s_barrier();
    asm volatile("s_waitcnt lgkmcnt(0)" ::: "memory");
    __builtin_amdgcn_sched_barrier(0);
    __builtin_amdgcn_s_setprio(1);
#pragma unroll
    for (int i = 0; i < 4; ++i)
#pragma unroll
      for (int jj = 0; jj < 4; ++jj)
        acc[i][jj] = __builtin_amdgcn_mfma_f32_16x16x32_bf16(af[i], bfr[jj], acc[i][jj], 0, 0, 0);
    __builtin_amdgcn_s_setprio(0);
    __builtin_amdgcn_sched_barrier(0);
    __builtin_amdgcn_s_barrier();

    // ---------- phase B: stage B-half of tile k+3 ∥ ds_read A-hi; MFMA acc[4..7] ----------
    if (pf) stageB(k + 3);
    bf16x8 ag[4];
#pragma unroll
    for (int i = 0; i < 4; ++i) ag[i] = *(bf16x8*)(&LDS[bb + aoff[4 + i]]);
    __builtin_amdgcn_s_barrier();
    asm volatile("s_waitcnt lgkmcnt(0)" ::: "memory");
    __builtin_amdgcn_sched_barrier(0);
    __builtin_amdgcn_s_setprio(1);
#pragma unroll
    for (int i = 0; i < 4; ++i)
#pragma unroll
      for (int jj = 0; jj < 4; ++jj)
        acc[4 + i][jj] = __builtin_amdgcn_mfma_f32_16x16x32_bf16(ag[i], bfr[jj], acc[4 + i][jj], 0, 0, 0);
    __builtin_amdgcn_s_setprio(0);
    __builtin_amdgcn_sched_barrier(0);
    if (k < KT - 1){
      // counted drain: ensure tile k+1 landed; keep later tiles in flight (never 0 until epilogue)
      if (k < KT - 3)       { asm volatile("s_waitcnt vmcnt(8)" ::: "memory"); }
      else if (k == KT - 3) { asm volatile("s_waitcnt vmcnt(4)" ::: "memory"); }
      else                  { asm volatile("s_waitcnt vmcnt(0)" ::: "memory"); }
    }
    __builtin_amdgcn_s_barrier();
  }

  // ---- epilogue: C/D layout col=lane&15, row=quad*4+reg; column-split dual output ----
  if (row0 + BM2 <= M){
#pragma unroll
    for (int i = 0; i < 8; ++i){
#pragma unroll
      for (int jj = 0; jj < 4; ++jj){
        int gc = col0 + wc + jj * 16 + l15;
        if (gc < Ntot){
          bf16* Cp = (gc < HID) ? C0 : C1;
          size_t cc = (gc < HID) ? gc : gc - HID;
          size_t base = (size_t)(row0 + wr + i * 16 + quad * 4) * HID + cc;
#pragma unroll
          for (int r = 0; r < 4; ++r)
            Cp[base + (size_t)r * HID] = f2b(acc[i][jj][r]);
        }
      }
    }
  } else {
#pragma unroll
    for (int i = 0; i < 8; ++i){
#pragma unroll
      for (int jj = 0; jj < 4; ++jj){
        int gc = col0 + wc + jj * 16 + l15;
        if (gc < Ntot){
          bf16* Cp = (gc < HID) ? C0 : C1;
          int cc   = (gc < HID) ? gc : gc - HID;
#pragma unroll
          for (int r = 0; r < 4; ++r){
            int gr = row0 + wr + i * 16 + quad * 4 + r;
            if (gr < M) Cp[(size_t)gr * HID + cc] = f2b(acc[i][jj][r]);
          }
        }
      }
    }
  }
}

// ---------------------------------------------------------------- CSR build
__global__ __launch_bounds__(256) void count_deg(const int* __restrict__ edst, int* __restrict__ degi){
  int e = blockIdx.x * 256 + threadIdx.x;
  if (e >= N_EDGES) return;
  atomicAdd(&degi[clampi(edst[e], N_NODES)], 1);
}

// phase 1: per-block exclusive scan; block sums to bsum; dinv computed here
__global__ __launch_bounds__(256) void scan_blk(const int* __restrict__ degi,
                                                int* __restrict__ rowp,
                                                float* __restrict__ dinv,
                                                int* __restrict__ bsum){
  __shared__ int wsum[4];
  int b = blockIdx.x, tid = threadIdx.x;
  int i = b * 256 + tid;
  int lane = tid & 63, wv = tid >> 6;
  int v = (i < N_NODES) ? degi[i] : 0;
  int incl = v;
#pragma unroll
  for (int ofs = 1; ofs < 64; ofs <<= 1){
    int t = __shfl_up(incl, ofs);
    if (lane >= ofs) incl += t;
  }
  if (lane == 63) wsum[wv] = incl;
  __syncthreads();
  int woff = 0;
#pragma unroll
  for (int w = 0; w < 4; ++w) if (w < wv) woff += wsum[w];
  if (i < N_NODES){
    rowp[i] = woff + incl - v;            // block-local exclusive
    dinv[i] = rsqrtf((float)(v + 1));
  }
  if (tid == 0) bsum[b] = wsum[0] + wsum[1] + wsum[2] + wsum[3];
}

// phase 2: single block scans bsum[SCB] exclusive in place; total -> rowp[N_NODES]
__global__ __launch_bounds__(256) void scan_top(int* __restrict__ bsum, int* __restrict__ rowp){
  __shared__ int wsum[4];
  int tid = threadIdx.x, lane = tid & 63, wv = tid >> 6;
  int v = (tid < SCB) ? bsum[tid] : 0;
  int incl = v;
#pragma unroll
  for (int ofs = 1; ofs < 64; ofs <<= 1){
    int t = __shfl_up(incl, ofs);
    if (lane >= ofs) incl += t;
  }
  if (lane == 63) wsum[wv] = incl;
  __syncthreads();
  int woff = 0;
#pragma unroll
  for (int w = 0; w < 4; ++w) if (w < wv) woff += wsum[w];
  if (tid < SCB) bsum[tid] = woff + incl - v;
  if (tid == 255) rowp[N_NODES] = woff + incl;   // grand total (v=0 past SCB)
}

// phase 3: add block offsets; curs = rowp
__global__ __launch_bounds__(256) void scan_add(const int* __restrict__ bsum,
                                                int* __restrict__ rowp,
                                                int* __restrict__ curs){
  int i = blockIdx.x * 256 + threadIdx.x;
  if (i >= N_NODES) return;
  int r = rowp[i] + bsum[blockIdx.x];
  rowp[i] = r; curs[i] = r;
}

__global__ __launch_bounds__(256) void bucket_edges(const int* __restrict__ esrc,
                                                    const int* __restrict__ edst,
                                                    int* __restrict__ curs,
                                                    int* __restrict__ srcg,
                                                    int* __restrict__ dstg){
  int e = blockIdx.x * 256 + threadIdx.x;
  if (e >= N_EDGES) return;
  int d = clampi(edst[e], N_NODES);
  int pos = atomicAdd(&curs[d], 1);
  srcg[pos] = clampi(esrc[e], N_NODES);
  dstg[pos] = d;
}

// ---------------------------------------------------------------- GAT1 fused logits+aggregation
// lane l owns ch [8l,8l+8) (head l>>3) and ch {512+2l,513+2l} (head 8+(l>>5)).
// Logit per head: 3-step shfl_xor reduce within 8-lane group (heads 0-7);
// 5-step reduce within 32-lane half (heads 8,9). Online softmax (branchless rescale).
__global__ __launch_bounds__(256) void gat1_fused(const bf16* __restrict__ xl,
                                                  const bf16* __restrict__ xr,
                                                  const int* __restrict__ srcg,
                                                  const int* __restrict__ rowp,
                                                  const float* __restrict__ att,
                                                  const float* __restrict__ bias,
                                                  bf16* __restrict__ H){
  int n    = (blockIdx.x * 256 + threadIdx.x) >> 6;
  int lane = threadIdx.x & 63;
  if (n >= N_NODES) return;
  int r0 = rowp[n], r1 = rowp[n + 1];

  // attention weights for this lane's channels (att is [10][64] row-major => ch-major)
  float4 aA0 = *(const float4*)(att + 8 * lane);
  float4 aA1 = *(const float4*)(att + 8 * lane + 4);
  float2 aBv = *(const float2*)(att + 512 + 2 * lane);
  float attA[8] = {aA0.x, aA0.y, aA0.z, aA0.w, aA1.x, aA1.y, aA1.z, aA1.w};
  float attB0 = aBv.x, attB1 = aBv.y;

  // xr[n] (target transform) for this lane's channels
  const bf16* xrn = xr + (size_t)n * HID;
  bf16x8 vr = *(const bf16x8*)(xrn + 8 * lane);
  unsigned ur = *(const unsigned*)(xrn + 512 + 2 * lane);
  float xrA[8];
#pragma unroll
  for (int j = 0; j < 8; ++j) xrA[j] = bf2f_bits(vr[j]);
  float xrB0 = bf2f_bits((short)(ur & 0xffff));
  float xrB1 = bf2f_bits((short)(ur >> 16));

  // logit from a gathered source row (per-lane channels) -> per-lane head logits
  auto logits = [&](const float* xA, float xB0, float xB1, float& lA, float& lB){
    float pa = 0.f;
#pragma unroll
    for (int j = 0; j < 8; ++j){
      float s = xA[j] + xrA[j];
      s *= (s > 0.f) ? 1.f : NEG_SLOPE;
      pa = fmaf(attA[j], s, pa);
    }
    pa += __shfl_xor(pa, 1);
    pa += __shfl_xor(pa, 2);
    pa += __shfl_xor(pa, 4);
    lA = pa;
    float s0 = xB0 + xrB0; s0 *= (s0 > 0.f) ? 1.f : NEG_SLOPE;
    float s1 = xB1 + xrB1; s1 *= (s1 > 0.f) ? 1.f : NEG_SLOPE;
    float pb = attB0 * s0 + attB1 * s1;
    pb += __shfl_xor(pb, 1);
    pb += __shfl_xor(pb, 2);
    pb += __shfl_xor(pb, 4);
    pb += __shfl_xor(pb, 8);
    pb += __shfl_xor(pb, 16);
    lB = pb;
  };

  // self-loop init
  const bf16* xn = xl + (size_t)n * HID;
  bf16x8 v0 = *(const bf16x8*)(xn + 8 * lane);
  unsigned u0 = *(const unsigned*)(xn + 512 + 2 * lane);
  float accA[8];
  float sA[8];
#pragma unroll
  for (int j = 0; j < 8; ++j){ sA[j] = bf2f_bits(v0[j]); accA[j] = sA[j]; }
  float sB0 = bf2f_bits((short)(u0 & 0xffff));
  float sB1 = bf2f_bits((short)(u0 >> 16));
  float accB0 = sB0, accB1 = sB1;
  float mA, mB;
  logits(sA, sB0, sB1, mA, mB);
  float denA = 1.f, denB = 1.f;

  int p = r0;
  for (; p + 1 < r1; p += 2){
    int s0i = srcg[p], s1i = srcg[p + 1];
    const bf16* q0 = xl + (size_t)s0i * HID;
    const bf16* q1 = xl + (size_t)s1i * HID;
    bf16x8 w0 = *(const bf16x8*)(q0 + 8 * lane);
    unsigned t0 = *(const unsigned*)(q0 + 512 + 2 * lane);
    bf16x8 w1 = *(const bf16x8*)(q1 + 8 * lane);
    unsigned t1 = *(const unsigned*)(q1 + 512 + 2 * lane);
    float yA0[8], yA1[8];
#pragma unroll
    for (int j = 0; j < 8; ++j){ yA0[j] = bf2f_bits(w0[j]); yA1[j] = bf2f_bits(w1[j]); }
    float yB00 = bf2f_bits((short)(t0 & 0xffff)), yB01 = bf2f_bits((short)(t0 >> 16));
    float yB10 = bf2f_bits((short)(t1 & 0xffff)), yB11 = bf2f_bits((short)(t1 >> 16));
    float lA0, lB0, lA1, lB1;
    logits(yA0, yB00, yB01, lA0, lB0);
    logits(yA1, yB10, yB11, lA1, lB1);
    // combined online-softmax update (A heads)
    {
      float m2 = fmaxf(mA, fmaxf(lA0, lA1));
      float sc = __expf(mA - m2);
      float p0 = __expf(lA0 - m2), p1 = __expf(lA1 - m2);
      denA = denA * sc + p0 + p1; mA = m2;
#pragma unroll
      for (int j = 0; j < 8; ++j) accA[j] = accA[j] * sc + p0 * yA0[j] + p1 * yA1[j];
    }
    // (B heads)
    {
      float m2 = fmaxf(mB, fmaxf(lB0, lB1));
      float sc = __expf(mB - m2);
      float p0 = __expf(lB0 - m2), p1 = __expf(lB1 - m2);
      denB = denB * sc + p0 + p1; mB = m2;
      accB0 = accB0 * sc + p0 * yB00 + p1 * yB10;
      accB1 = accB1 * sc + p0 * yB01 + p1 * yB11;
    }
  }
  if (p < r1){
    int si = srcg[p];
    const bf16* q0 = xl + (size_t)si * HID;
    bf16x8 w0 = *(const bf16x8*)(q0 + 8 * lane);
    unsigned t0 = *(const unsigned*)(q0 + 512 + 2 * lane);
    float yA0[8];
#pragma unroll
    for (int j = 0; j < 8; ++j) yA0[j] = bf2f_bits(w0[j]);
    float yB00 = bf2f_bits((short)(t0 & 0xffff)), yB01 = bf2f_bits((short)(t0 >> 16));
    float lA0, lB0;
    logits(yA0, yB00, yB01, lA0, lB0);
    {
      float m2 = fmaxf(mA, lA0);
      float sc = __expf(mA - m2);
      float p0 = __expf(lA0 - m2);
      denA = denA * sc + p0; mA = m2;
#pragma unroll
      for (int j = 0; j < 8; ++j) accA[j] = accA[j] * sc + p0 * yA0[j];
    }
    {
      float m2 = fmaxf(mB, lB0);
      float sc = __expf(mB - m2);
      float p0 = __expf(lB0 - m2);
      denB = denB * sc + p0; mB = m2;
      accB0 = accB0 * sc + p0 * yB00;
      accB1 = accB1 * sc + p0 * yB01;
    }
  }

  float invA = 1.f / denA, invB = 1.f / denB;
  float4 bA0 = *(const float4*)(bias + 8 * lane);
  float4 bA1 = *(const float4*)(bias + 8 * lane + 4);
  float2 bB  = *(const float2*)(bias + 512 + 2 * lane);
  float bAa[8] = {bA0.x, bA0.y, bA0.z, bA0.w, bA1.x, bA1.y, bA1.z, bA1.w};
  bf16x8 oA;
#pragma unroll
  for (int j = 0; j < 8; ++j){
    float v = accA[j] * invA + bAa[j];
    v = v > 0.f ? v : (__expf(v) - 1.f);              // ELU
    oA[j] = f2bf_bits(v);
  }
  float vb0 = accB0 * invB + bB.x; vb0 = vb0 > 0.f ? vb0 : (__expf(vb0) - 1.f);
  float vb1 = accB1 * invB + bB.y; vb1 = vb1 > 0.f ? vb1 : (__expf(vb1) - 1.f);
  bf16* hn = H + (size_t)n * HID;
  *(bf16x8*)(hn + 8 * lane) = oA;
  unsigned ob = (unsigned)(unsigned short)f2bf_bits(vb0) |
                ((unsigned)(unsigned short)f2bf_bits(vb1) << 16);
  *(unsigned*)(hn + 512 + 2 * lane) = ob;
}

// ---------------------------------------------------------------- GAT2 fused (1 head, full-wave logit reduce)
__global__ __launch_bounds__(256) void gat2_fused(const bf16* __restrict__ xl,
                                                  const bf16* __restrict__ xr,
                                                  const int* __restrict__ srcg,
                                                  const int* __restrict__ rowp,
                                                  const float* __restrict__ att,
                                                  const float* __restrict__ bias,
                                                  bf16* __restrict__ H){
  int n    = (blockIdx.x * 256 + threadIdx.x) >> 6;
  int lane = threadIdx.x & 63;
  if (n >= N_NODES) return;
  int r0 = rowp[n], r1 = rowp[n + 1];

  float4 aA0 = *(const float4*)(att + 8 * lane);
  float4 aA1 = *(const float4*)(att + 8 * lane + 4);
  float2 aBv = *(const float2*)(att + 512 + 2 * lane);
  float attA[8] = {aA0.x, aA0.y, aA0.z, aA0.w, aA1.x, aA1.y, aA1.z, aA1.w};
  float attB0 = aBv.x, attB1 = aBv.y;

  const bf16* xrn = xr + (size_t)n * HID;
  bf16x8 vr = *(const bf16x8*)(xrn + 8 * lane);
  unsigned ur = *(const unsigned*)(xrn + 512 + 2 * lane);
  float xrA[8];
#pragma unroll
  for (int j = 0; j < 8; ++j) xrA[j] = bf2f_bits(vr[j]);
  float xrB0 = bf2f_bits((short)(ur & 0xffff));
  float xrB1 = bf2f_bits((short)(ur >> 16));

  auto logit1 = [&](const float* xA, float xB0, float xB1)->float{
    float s0 = xB0 + xrB0; s0 *= (s0 > 0.f) ? 1.f : NEG_SLOPE;
    float s1 = xB1 + xrB1; s1 *= (s1 > 0.f) ? 1.f : NEG_SLOPE;
    float pa = attB0 * s0 + attB1 * s1;
#pragma unroll
    for (int j = 0; j < 8; ++j){
      float s = xA[j] + xrA[j];
      s *= (s > 0.f) ? 1.f : NEG_SLOPE;
      pa = fmaf(attA[j], s, pa);
    }
    pa += __shfl_xor(pa, 1);
    pa += __shfl_xor(pa, 2);
    pa += __shfl_xor(pa, 4);
    pa += __shfl_xor(pa, 8);
    pa += __shfl_xor(pa, 16);
    pa += __shfl_xor(pa, 32);
    return pa;
  };

  const bf16* xn = xl + (size_t)n * HID;
  bf16x8 v0 = *(const bf16x8*)(xn + 8 * lane);
  unsigned u0 = *(const unsigned*)(xn + 512 + 2 * lane);
  float accA[8];
  float sA[8];
#pragma unroll
  for (int j = 0; j < 8; ++j){ sA[j] = bf2f_bits(v0[j]); accA[j] = sA[j]; }
  float sB0 = bf2f_bits((short)(u0 & 0xffff));
  float sB1 = bf2f_bits((short)(u0 >> 16));
  float accB0 = sB0, accB1 = sB1;
  float m = logit1(sA, sB0, sB1);
  float den = 1.f;

  int p = r0;
  for (; p + 1 < r1; p += 2){
    int s0i = srcg[p], s1i = srcg[p + 1];
    const bf16* q0 = xl + (size_t)s0i * HID;
    const bf16* q1 = xl + (size_t)s1i * HID;
    bf16x8 w0 = *(const bf16x8*)(q0 + 8 * lane);
    unsigned t0 = *(const unsigned*)(q0 + 512 + 2 * lane);
    bf16x8 w1 = *(const bf16x8*)(q1 + 8 * lane);
    unsigned t1 = *(const unsigned*)(q1 + 512 + 2 * lane);
    float yA0[8], yA1[8];
#pragma unroll
    for (int j = 0; j < 8; ++j){ yA0[j] = bf2f_bits(w0[j]); yA1[j] = bf2f_bits(w1[j]); }
    float yB00 = bf2f_bits((short)(t0 & 0xffff)), yB01 = bf2f_bits((short)(t0 >> 16));
    float yB10 = bf2f_bits((short)(t1 & 0xffff)), yB11 = bf2f_bits((short)(t1 >> 16));
    float l0 = logit1(yA0, yB00, yB01);
    float l1 = logit1(yA1, yB10, yB11);
    float m2 = fmaxf(m, fmaxf(l0, l1));
    float sc = __expf(m - m2);
    float p0 = __expf(l0 - m2), p1 = __expf(l1 - m2);
    den = den * sc + p0 + p1; m = m2;
#pragma unroll
    for (int j = 0; j < 8; ++j) accA[j] = accA[j] * sc + p0 * yA0[j] + p1 * yA1[j];
    accB0 = accB0 * sc + p0 * yB00 + p1 * yB10;
    accB1 = accB1 * sc + p0 * yB01 + p1 * yB11;
  }
  if (p < r1){
    int si = srcg[p];
    const bf16* q0 = xl + (size_t)si * HID;
    bf16x8 w0 = *(const bf16x8*)(q0 + 8 * lane);
    unsigned t0 = *(const unsigned*)(q0 + 512 + 2 * lane);
    float yA0[8];
#pragma unroll
    for (int j = 0; j < 8; ++j) yA0[j] = bf2f_bits(w0[j]);
    float yB00 = bf2f_bits((short)(t0 & 0xffff)), yB01 = bf2f_bits((short)(t0 >> 16));
    float l0 = logit1(yA0, yB00, yB01);
    float m2 = fmaxf(m, l0);
    float sc = __expf(m - m2);
    float p0 = __expf(l0 - m2);
    den = den * sc + p0; m = m2;
#pragma unroll
    for (int j = 0; j < 8; ++j) accA[j] = accA[j] * sc + p0 * yA0[j];
    accB0 = accB0 * sc + p0 * yB00;
    accB1 = accB1 * sc + p0 * yB01;
  }

  float inv = 1.f / den;
  float4 bA0 = *(const float4*)(bias + 8 * lane);
  float4 bA1 = *(const float4*)(bias + 8 * lane + 4);
  float2 bB  = *(const float2*)(bias + 512 + 2 * lane);
  float bAa[8] = {bA0.x, bA0.y, bA0.z, bA0.w, bA1.x, bA1.y, bA1.z, bA1.w};
  bf16x8 oA;
#pragma unroll
  for (int j = 0; j < 8; ++j) oA[j] = f2bf_bits(accA[j] * inv + bAa[j]);
  bf16* hn = H + (size_t)n * HID;
  *(bf16x8*)(hn + 8 * lane) = oA;
  unsigned ob = (unsigned)(unsigned short)f2bf_bits(accB0 * inv + bB.x) |
                ((unsigned)(unsigned short)f2bf_bits(accB1 * inv + bB.y) << 16);
  *(unsigned*)(hn + 512 + 2 * lane) = ob;
}

// ---------------------------------------------------------------- GCN gather: bias+ReLU -> bf16 h3 (unrolled)
__global__ __launch_bounds__(256) void gcn_gather(const bf16* __restrict__ xw,
                                                  const int* __restrict__ srcg,
                                                  const int* __restrict__ rowp,
                                                  const float* __restrict__ dinv,
                                                  const float* __restrict__ bg,
                                                  bf16* __restrict__ h3){
  int n    = (blockIdx.x * 256 + threadIdx.x) >> 6;
  int lane = threadIdx.x & 63;
  if (n >= N_NODES) return;
  int r0 = rowp[n], r1 = rowp[n + 1];

  float dn = dinv[n];
  float accA[8], accB[2];
  {
    float w = dn * dn;
    const bf16* xn = xw + (size_t)n * HID;
    bf16x8 va = *(const bf16x8*)(xn + 8 * lane);
    unsigned vb = *(const unsigned*)(xn + 512 + 2 * lane);
#pragma unroll
    for (int j = 0; j < 8; ++j) accA[j] = w * bf2f_bits(va[j]);
    accB[0] = w * bf2f_bits((short)(vb & 0xffff));
    accB[1] = w * bf2f_bits((short)(vb >> 16));
  }
  int p = r0;
  for (; p + 1 < r1; p += 2){
    int s0 = srcg[p], s1 = srcg[p + 1];
    float w0 = dinv[s0] * dn, w1 = dinv[s1] * dn;
    const bf16* xs0 = xw + (size_t)s0 * HID;
    const bf16* xs1 = xw + (size_t)s1 * HID;
    bf16x8 va0 = *(const bf16x8*)(xs0 + 8 * lane);
    bf16x8 va1 = *(const bf16x8*)(xs1 + 8 * lane);
    unsigned vb0 = *(const unsigned*)(xs0 + 512 + 2 * lane);
    unsigned vb1 = *(const unsigned*)(xs1 + 512 + 2 * lane);
#pragma unroll
    for (int j = 0; j < 8; ++j) accA[j] += w0 * bf2f_bits(va0[j]) + w1 * bf2f_bits(va1[j]);
    accB[0] += w0 * bf2f_bits((short)(vb0 & 0xffff)) + w1 * bf2f_bits((short)(vb1 & 0xffff));
    accB[1] += w0 * bf2f_bits((short)(vb0 >> 16))    + w1 * bf2f_bits((short)(vb1 >> 16));
  }
  if (p < r1){
    int s = srcg[p];
    float w = dinv[s] * dn;
    const bf16* xs = xw + (size_t)s * HID;
    bf16x8 va = *(const bf16x8*)(xs + 8 * lane);
    unsigned vb = *(const unsigned*)(xs + 512 + 2 * lane);
#pragma unroll
    for (int j = 0; j < 8; ++j) accA[j] += w * bf2f_bits(va[j]);
    accB[0] += w * bf2f_bits((short)(vb & 0xffff));
    accB[1] += w * bf2f_bits((short)(vb >> 16));
  }
  float4 bA0 = *(const float4*)(bg + 8 * lane);
  float4 bA1 = *(const float4*)(bg + 8 * lane + 4);
  float2 bB  = *(const float2*)(bg + 512 + 2 * lane);
  float bAa[8] = {bA0.x, bA0.y, bA0.z, bA0.w, bA1.x, bA1.y, bA1.z, bA1.w};
  bf16x8 oA;
#pragma unroll
  for (int j = 0; j < 8; ++j) oA[j] = f2bf_bits(fmaxf(accA[j] + bAa[j], 0.f));
  bf16* hn = h3 + (size_t)n * HID;
  *(bf16x8*)(hn + 8 * lane) = oA;
  unsigned ob = (unsigned)(unsigned short)f2bf_bits(fmaxf(accB[0] + bB.x, 0.f)) |
                ((unsigned)(unsigned short)f2bf_bits(fmaxf(accB[1] + bB.y, 0.f)) << 16);
  *(unsigned*)(hn + 512 + 2 * lane) = ob;
}

// ---------------------------------------------------------------- per-graph pooling (batch is sorted)
__global__ __launch_bounds__(256) void graph_bounds(const int* __restrict__ batch,
                                                    int* __restrict__ gstart){
  int n = blockIdx.x * 256 + threadIdx.x;
  if (n >= N_NODES) return;
  int b = clampi(batch[n], N_GRAPHS);
  if (n == 0){
    for (int g = 0; g <= b; ++g) gstart[g] = 0;
  } else {
    int bp = clampi(batch[n - 1], N_GRAPHS);
    for (int g = bp + 1; g <= b; ++g) gstart[g] = n;
  }
  if (n == N_NODES - 1){
    for (int g = b + 1; g <= N_GRAPHS; ++g) gstart[g] = N_NODES;
  }
}

__global__ __launch_bounds__(640) void pool_graph(const bf16* __restrict__ h3,
                                                  const int* __restrict__ gstart,
                                                  float* __restrict__ out){
  int g = blockIdx.x;
  int c = threadIdx.x;
  int n0 = gstart[g], n1 = gstart[g + 1];
  float mx = 0.f, sm = 0.f;     // h3 >= 0 post-ReLU
  for (int n = n0; n < n1; ++n){
    float v = b2f(h3[(size_t)n * HID + c]);
    mx = fmaxf(mx, v); sm += v;
  }
  float mean = (n1 > n0) ? sm / (float)(n1 - n0) : 0.f;
  out[(size_t)g * 2 * HID + c]       = mx;
  out[(size_t)g * 2 * HID + HID + c] = mean;
}

// ---------------------------------------------------------------- launch
extern "C" void kernel_launch(void* const* d_in, const int* in_sizes, int n_in,
                              void* d_out, int out_size, void* d_ws, size_t ws_size,
                              hipStream_t stream){
  const float* x     = (const float*)d_in[0];
  const int*   ei    = (const int*)d_in[1];
  const int*   batch = (const int*)d_in[2];
  const float* Wl1 = (const float*)d_in[3];
  const float* Wr1 = (const float*)d_in[4];
  const float* a1  = (const float*)d_in[5];
  const float* b1  = (const float*)d_in[6];
  const float* Wl2 = (const float*)d_in[7];
  const float* Wr2 = (const float*)d_in[8];
  const float* a2  = (const float*)d_in[9];
  const float* b2  = (const float*)d_in[10];
  const float* Wg  = (const float*)d_in[11];
  const float* bg  = (const float*)d_in[12];
  const int* esrc = ei;
  const int* edst = ei + N_EDGES;

  // ---- workspace layout ----
  char* ws = (char*)d_ws;
  size_t off = 0;
  auto take = [&](size_t bytes)->char*{
    char* p = ws + off; off = (off + bytes + 255) & ~(size_t)255; return p;
  };
  bf16*     X1   = (bf16*)    take((size_t)N_NODES * HID * 2);
  bf16*     X2   = (bf16*)    take((size_t)N_NODES * HID * 2);
  bf16*     H    = (bf16*)    take((size_t)N_NODES * HID * 2);
  bf16*     XB   = (bf16*)    take((size_t)N_NODES * K1P * 2);
  // WT1l|WT1r contiguous (one 1280xK1P matrix); WT2l|WT2r|WTg contiguous.
  bf16*     WT1l = (bf16*)    take((size_t)HID * K1P * 2);
  bf16*     WT1r = (bf16*)    take((size_t)HID * K1P * 2);
  bf16*     WT2l = (bf16*)    take((size_t)HID * HID * 2);
  bf16*     WT2r = (bf16*)    take((size_t)HID * HID * 2);
  bf16*     WTg  = (bf16*)    take((size_t)HID * HID * 2);
  int*      DEGI = (int*)     take((size_t)N_NODES * 4);
  int*      ROWP = (int*)     take((size_t)(N_NODES + 1) * 4);
  int*      CURS = (int*)     take((size_t)N_NODES * 4);
  int*      SRCG = (int*)     take((size_t)N_EDGES * 4);
  int*      DSTG = (int*)     take((size_t)N_EDGES * 4);
  float*    DINV = (float*)   take((size_t)N_NODES * 4);
  int*      GST  = (int*)     take((size_t)(N_GRAPHS + 1) * 4);
  int*      BSUM = (int*)     take((size_t)SCB * 4);
  (void)WT1r; (void)WT2r; (void)DSTG;

  dim3 blk(256);
  auto fill = [&](void* p, unsigned v, int n){
    fill_u32<<<dim3((n + 255) / 256), blk, 0, stream>>>((unsigned*)p, v, n);
  };
  const int MB8     = ((N_NODES + BM - 1) / BM + 7) / 8;     // 128-row strips per XCD (49)
  const int MB28    = ((N_NODES + BM2 - 1) / BM2 + 7) / 8;   // 256-row strips per XCD (25)
  const int nblocks = (N_NODES * 64 + 255) / 256;
  const int reblk   = (N_EDGES + 255) / 256;

  // ---- prep + CSR ----
  conv_x<<<(N_NODES * K1P + 255) / 256, blk, 0, stream>>>(x, XB);
  conv_wT2<<<(2 * HID * K1P + 255) / 256, blk, 0, stream>>>(Wl1, Wr1, WT1l, IN_DIM, HID, K1P);
  conv_wT3t<<<dim3(HID / 32, HID / 32, 3), blk, 0, stream>>>(Wl2, Wr2, Wg, WT2l);
  fill(DEGI, 0u, N_NODES);
  count_deg<<<reblk, blk, 0, stream>>>(edst, DEGI);
  scan_blk<<<dim3(SCB), blk, 0, stream>>>(DEGI, ROWP, DINV, BSUM);
  scan_top<<<dim3(1), blk, 0, stream>>>(BSUM, ROWP);
  scan_add<<<dim3(SCB), blk, 0, stream>>>(BSUM, ROWP, CURS);
  bucket_edges<<<reblk, blk, 0, stream>>>(esrc, edst, CURS, SRCG, DSTG);
  graph_bounds<<<(N_NODES + 255) / 256, blk, 0, stream>>>(batch, GST);

  // ---- GATv2 layer 1 (merged Wl|Wr GEMM, K=128 shallow -> 128^2 kernel; fused logits+agg) ----
  mfma_gemm<<<dim3(8 * MB8 * 10), blk, 0, stream>>>(XB, WT1l, X1, X2, N_NODES, K1P, 10);
  gat1_fused<<<nblocks, blk, 0, stream>>>(X1, X2, SRCG, ROWP, a1, b1, H);

  // ---- GATv2 layer 2 (merged Wl|Wr GEMM, N=1280, K=640 -> 256^2 8-phase; fused logits+agg) ----
  mfma_gemm2<<<dim3(8 * MB28 * 5), dim3(512), 0, stream>>>(H, WT2l, X1, X2, N_NODES, 2 * HID, HID, 5);
  gat2_fused<<<nblocks, blk, 0, stream>>>(X1, X2, SRCG, ROWP, a2, b2, H);

  // ---- GCN (N=640, K=640 -> 256^2 8-phase, partial last N-tile) + pooling ----
  mfma_gemm2<<<dim3(8 * MB28 * 3), dim3(512), 0, stream>>>(H, WTg, X1, X1, N_NODES, HID, HID, 3);
  gcn_gather<<<nblocks, blk, 0, stream>>>(X1, SRCG, ROWP, DINV, bg, X2);
  pool_graph<<<dim3(N_GRAPHS), dim3(640), 0, stream>>>(X2, GST, (float*)d_out);
}

// Round 5
// 499.375 us; speedup vs baseline: 1.0510x; 1.0510x over previous
//
#include <hip/hip_runtime.h>
#include <hip/hip_bf16.h>
#include <cstdint>
#include <cstddef>

typedef __hip_bfloat16 bf16;

#define N_NODES  50000
#define N_EDGES  150000
#define N_GRAPHS 1024
#define IN_DIM   78
#define K1P      128                   /* IN_DIM padded to mult of 64 (BK) */
#define OUT_DIM  64
#define HEADS    10
#define HID      640
#define NEG_SLOPE 0.2f
#define SCB      ((N_NODES + 255) / 256)   /* 196 scan blocks */

static __device__ __forceinline__ float b2f(bf16 v){ return __bfloat162float(v); }
static __device__ __forceinline__ bf16  f2b(float v){ return __float2bfloat16(v); }

__device__ __forceinline__ int clampi(int v, int hi){ return v < 0 ? 0 : (v >= hi ? hi - 1 : v); }

__device__ __forceinline__ float bf2f_bits(short s){
  return __uint_as_float(((unsigned)(unsigned short)s) << 16);
}
__device__ __forceinline__ short f2bf_bits(float v){      // RNE
  unsigned u = __float_as_uint(v);
  return (short)((u + 0x7fffu + ((u >> 16) & 1u)) >> 16);
}

// ---------------------------------------------------------------- fills
__global__ __launch_bounds__(256) void fill_u32(unsigned* __restrict__ p, unsigned v, int n){
  int i = blockIdx.x * 256 + threadIdx.x;
  if (i < n) p[i] = v;
}

// ---------------------------------------------------------------- dtype prep
__global__ __launch_bounds__(256) void conv_x(const float* __restrict__ x, bf16* __restrict__ XB){
  int i = blockIdx.x * 256 + threadIdx.x;
  if (i >= N_NODES * K1P) return;
  int n = i / K1P, k = i - n * K1P;
  XB[i] = f2b(k < IN_DIM ? x[(size_t)n * IN_DIM + k] : 0.f);
}

// 2 weight matrices -> contiguous transposed bf16 (layer-1 pair, K padded; small)
__global__ __launch_bounds__(256) void conv_wT2(const float* __restrict__ W0,
                                                const float* __restrict__ W1,
                                                bf16* __restrict__ WT,
                                                int K, int N, int Kp){
  int i = blockIdx.x * 256 + threadIdx.x;
  const int per = N * Kp;
  if (i >= 2 * per) return;
  int m = i / per, r = i - m * per;
  const float* W = m == 0 ? W0 : W1;
  int n = r / Kp, k = r - n * Kp;
  WT[i] = f2b(k < K ? W[(size_t)k * N + n] : 0.f);
}

// tiled transpose: 3x (640x640 f32, row-major k x n) -> bf16 WT[m][n][k]
__global__ __launch_bounds__(256) void conv_wT3t(const float* __restrict__ W0,
                                                 const float* __restrict__ W1,
                                                 const float* __restrict__ W2,
                                                 bf16* __restrict__ WT){
  __shared__ float t[32][33];
  int m = blockIdx.z;
  const float* W = m == 0 ? W0 : (m == 1 ? W1 : W2);
  int n0 = blockIdx.x * 32, k0 = blockIdx.y * 32;
  int tx = threadIdx.x & 31, ty = threadIdx.x >> 5;   // 32 x 8
#pragma unroll
  for (int r = 0; r < 32; r += 8)
    t[ty + r][tx] = W[(size_t)(k0 + ty + r) * HID + n0 + tx];   // coalesced in n
  __syncthreads();
  bf16* O = WT + (size_t)m * HID * HID;
#pragma unroll
  for (int r = 0; r < 32; r += 8)
    O[(size_t)(n0 + ty + r) * HID + k0 + tx] = f2b(t[tx][ty + r]);  // coalesced in k
}

// ---------------------------------------------------------------- MFMA GEMM (BK=64)
#define BM 128
#define BN 128
#define BK 64

typedef __attribute__((ext_vector_type(8))) short bf16x8;
typedef __attribute__((ext_vector_type(4))) float f32x4;

typedef const __attribute__((address_space(1))) unsigned gu32;
typedef __attribute__((address_space(3))) unsigned lu32;

__global__ __launch_bounds__(256) void mfma_gemm(const bf16* __restrict__ A,
                                                 const bf16* __restrict__ BT,
                                                 bf16* __restrict__ C0,
                                                 bf16* __restrict__ C1,
                                                 int M, int Kp, int NB){
  // block swizzle: all NB col-tiles of a row strip stay on one XCD (d%8 = XCD round-robin)
  int d   = blockIdx.x;
  int xcd = d & 7, j = d >> 3;
  int cb  = j % NB, ri = j / NB;
  int rb  = ri * 8 + xcd;
  const int row0 = rb * BM;
  if (row0 >= M) return;
  const int col0 = cb * BN;

  // LDS slot (r, kc) holds source k-chunk kc ^ (r&7): full 32-bank coverage, 2-way (free)
  __shared__ short As[BM * BK];   // 16 KB
  __shared__ short Bs[BN * BK];   // 16 KB
  const int tid  = threadIdx.x;
  const int lane = tid & 63;
  const int wave = tid >> 6;
  const int wr   = (wave >> 1) * 64;
  const int wc   = (wave & 1) * 64;
  const int l15  = lane & 15;
  const int quad = lane >> 4;
  const int sw   = l15 & 7;       // row-XOR term (wr, i*16 are multiples of 8)

  const bf16* aptr[4];
  const bf16* bptr[4];
  lu32* lda[4];
  lu32* ldb[4];
#pragma unroll
  for (int t = 0; t < 4; ++t){
    int ci = (t * 4 + wave) * 64 + lane;
    int r  = ci >> 3;
    int sc = (ci & 7) ^ (r & 7);
    int gr = row0 + r; if (gr >= M) gr = M - 1;
    aptr[t] = A  + (size_t)gr * Kp + sc * 8;
    bptr[t] = BT + (size_t)(col0 + r) * Kp + sc * 8;
    lda[t]  = (lu32*)(&As[(t * 4 + wave) * 512]);
    ldb[t]  = (lu32*)(&Bs[(t * 4 + wave) * 512]);
  }

  f32x4 acc[4][4];
#pragma unroll
  for (int i = 0; i < 4; ++i)
#pragma unroll
    for (int jj = 0; jj < 4; ++jj) acc[i][jj] = (f32x4){0.f, 0.f, 0.f, 0.f};

  for (int k0 = 0; k0 < Kp; k0 += BK){
#pragma unroll
    for (int t = 0; t < 4; ++t){
      __builtin_amdgcn_global_load_lds((gu32*)(aptr[t] + k0), lda[t], 16, 0, 0);
      __builtin_amdgcn_global_load_lds((gu32*)(bptr[t] + k0), ldb[t], 16, 0, 0);
    }
    __syncthreads();

#pragma unroll
    for (int ks = 0; ks < 2; ++ks){
      const int slotA = ((ks * 4 + quad) ^ sw) * 8;
      bf16x8 af[4], bfr[4];
#pragma unroll
      for (int i = 0; i < 4; ++i)
        af[i] = *(bf16x8*)(&As[(wr + i * 16 + l15) * BK + slotA]);
#pragma unroll
      for (int jj = 0; jj < 4; ++jj)
        bfr[jj] = *(bf16x8*)(&Bs[(wc + jj * 16 + l15) * BK + slotA]);
#pragma unroll
      for (int i = 0; i < 4; ++i)
#pragma unroll
        for (int jj = 0; jj < 4; ++jj)
          acc[i][jj] = __builtin_amdgcn_mfma_f32_16x16x32_bf16(af[i], bfr[jj], acc[i][jj], 0, 0, 0);
    }
    __syncthreads();
  }

  // epilogue: C/D layout col=lane&15, row=quad*4+reg; column-split dual output
  if (row0 + BM <= M){          // full strip: no row guards
#pragma unroll
    for (int i = 0; i < 4; ++i){
#pragma unroll
      for (int jj = 0; jj < 4; ++jj){
        int gc = col0 + wc + jj * 16 + l15;
        bf16* Cp = (gc < HID) ? C0 : C1;
        size_t cc = (gc < HID) ? gc : gc - HID;
        size_t base = (size_t)(row0 + wr + i * 16 + quad * 4) * HID + cc;
#pragma unroll
        for (int r = 0; r < 4; ++r)
          Cp[base + (size_t)r * HID] = f2b(acc[i][jj][r]);
      }
    }
  } else {
#pragma unroll
    for (int i = 0; i < 4; ++i){
#pragma unroll
      for (int jj = 0; jj < 4; ++jj){
        int gc = col0 + wc + jj * 16 + l15;
        bf16* Cp = (gc < HID) ? C0 : C1;
        int cc   = (gc < HID) ? gc : gc - HID;
#pragma unroll
        for (int r = 0; r < 4; ++r){
          int gr = row0 + wr + i * 16 + quad * 4 + r;
          if (gr < M) Cp[(size_t)gr * HID + cc] = f2b(acc[i][jj][r]);
        }
      }
    }
  }
}

// ---------------------------------------------------------------- CSR build
__global__ __launch_bounds__(256) void count_deg(const int* __restrict__ edst, int* __restrict__ degi){
  int e = blockIdx.x * 256 + threadIdx.x;
  if (e >= N_EDGES) return;
  atomicAdd(&degi[clampi(edst[e], N_NODES)], 1);
}

// phase 1: per-block exclusive scan; block sums to bsum; dinv computed here
__global__ __launch_bounds__(256) void scan_blk(const int* __restrict__ degi,
                                                int* __restrict__ rowp,
                                                float* __restrict__ dinv,
                                                int* __restrict__ bsum){
  __shared__ int wsum[4];
  int b = blockIdx.x, tid = threadIdx.x;
  int i = b * 256 + tid;
  int lane = tid & 63, wv = tid >> 6;
  int v = (i < N_NODES) ? degi[i] : 0;
  int incl = v;
#pragma unroll
  for (int ofs = 1; ofs < 64; ofs <<= 1){
    int t = __shfl_up(incl, ofs);
    if (lane >= ofs) incl += t;
  }
  if (lane == 63) wsum[wv] = incl;
  __syncthreads();
  int woff = 0;
#pragma unroll
  for (int w = 0; w < 4; ++w) if (w < wv) woff += wsum[w];
  if (i < N_NODES){
    rowp[i] = woff + incl - v;            // block-local exclusive
    dinv[i] = rsqrtf((float)(v + 1));
  }
  if (tid == 0) bsum[b] = wsum[0] + wsum[1] + wsum[2] + wsum[3];
}

// phase 2: single block scans bsum[SCB] exclusive in place; total -> rowp[N_NODES]
__global__ __launch_bounds__(256) void scan_top(int* __restrict__ bsum, int* __restrict__ rowp){
  __shared__ int wsum[4];
  int tid = threadIdx.x, lane = tid & 63, wv = tid >> 6;
  int v = (tid < SCB) ? bsum[tid] : 0;
  int incl = v;
#pragma unroll
  for (int ofs = 1; ofs < 64; ofs <<= 1){
    int t = __shfl_up(incl, ofs);
    if (lane >= ofs) incl += t;
  }
  if (lane == 63) wsum[wv] = incl;
  __syncthreads();
  int woff = 0;
#pragma unroll
  for (int w = 0; w < 4; ++w) if (w < wv) woff += wsum[w];
  if (tid < SCB) bsum[tid] = woff + incl - v;
  if (tid == 255) rowp[N_NODES] = woff + incl;   // grand total (v=0 past SCB)
}

// phase 3: add block offsets; curs = rowp
__global__ __launch_bounds__(256) void scan_add(const int* __restrict__ bsum,
                                                int* __restrict__ rowp,
                                                int* __restrict__ curs){
  int i = blockIdx.x * 256 + threadIdx.x;
  if (i >= N_NODES) return;
  int r = rowp[i] + bsum[blockIdx.x];
  rowp[i] = r; curs[i] = r;
}

__global__ __launch_bounds__(256) void bucket_edges(const int* __restrict__ esrc,
                                                    const int* __restrict__ edst,
                                                    int* __restrict__ curs,
                                                    int* __restrict__ srcg,
                                                    int* __restrict__ dstg){
  int e = blockIdx.x * 256 + threadIdx.x;
  if (e >= N_EDGES) return;
  int d = clampi(edst[e], N_NODES);
  int pos = atomicAdd(&curs[d], 1);
  srcg[pos] = clampi(esrc[e], N_NODES);
  dstg[pos] = d;
}

// ---------------------------------------------------------------- GAT1 fused logits+aggregation
// lane l owns ch [8l,8l+8) (head l>>3) and ch {512+2l,513+2l} (head 8+(l>>5)).
// Logit per head: 3-step shfl_xor reduce within 8-lane group (heads 0-7);
// 5-step reduce within 32-lane half (heads 8,9). Online softmax (branchless rescale).
// Edge loop: 4-edge load-issue groups (T14 issue-early), processed as two pairs.
__global__ __launch_bounds__(256) void gat1_fused(const bf16* __restrict__ xl,
                                                  const bf16* __restrict__ xr,
                                                  const int* __restrict__ srcg,
                                                  const int* __restrict__ rowp,
                                                  const float* __restrict__ att,
                                                  const float* __restrict__ bias,
                                                  bf16* __restrict__ H){
  int n    = (blockIdx.x * 256 + threadIdx.x) >> 6;
  int lane = threadIdx.x & 63;
  if (n >= N_NODES) return;
  int r0 = rowp[n], r1 = rowp[n + 1];

  // attention weights for this lane's channels (att is [10][64] row-major => ch-major)
  float4 aA0 = *(const float4*)(att + 8 * lane);
  float4 aA1 = *(const float4*)(att + 8 * lane + 4);
  float2 aBv = *(const float2*)(att + 512 + 2 * lane);
  float attA[8] = {aA0.x, aA0.y, aA0.z, aA0.w, aA1.x, aA1.y, aA1.z, aA1.w};
  float attB0 = aBv.x, attB1 = aBv.y;

  // xr[n] (target transform) for this lane's channels
  const bf16* xrn = xr + (size_t)n * HID;
  bf16x8 vr = *(const bf16x8*)(xrn + 8 * lane);
  unsigned ur = *(const unsigned*)(xrn + 512 + 2 * lane);
  float xrA[8];
#pragma unroll
  for (int j = 0; j < 8; ++j) xrA[j] = bf2f_bits(vr[j]);
  float xrB0 = bf2f_bits((short)(ur & 0xffff));
  float xrB1 = bf2f_bits((short)(ur >> 16));

  // logit from a gathered source row (per-lane channels) -> per-lane head logits
  auto logits = [&](const float* xA, float xB0, float xB1, float& lA, float& lB){
    float pa = 0.f;
#pragma unroll
    for (int j = 0; j < 8; ++j){
      float s = xA[j] + xrA[j];
      s *= (s > 0.f) ? 1.f : NEG_SLOPE;
      pa = fmaf(attA[j], s, pa);
    }
    pa += __shfl_xor(pa, 1);
    pa += __shfl_xor(pa, 2);
    pa += __shfl_xor(pa, 4);
    lA = pa;
    float s0 = xB0 + xrB0; s0 *= (s0 > 0.f) ? 1.f : NEG_SLOPE;
    float s1 = xB1 + xrB1; s1 *= (s1 > 0.f) ? 1.f : NEG_SLOPE;
    float pb = attB0 * s0 + attB1 * s1;
    pb += __shfl_xor(pb, 1);
    pb += __shfl_xor(pb, 2);
    pb += __shfl_xor(pb, 4);
    pb += __shfl_xor(pb, 8);
    pb += __shfl_xor(pb, 16);
    lB = pb;
  };

  float accA[8], accB0, accB1, mA, mB, denA, denB;

  // self-loop init
  {
    const bf16* xn = xl + (size_t)n * HID;
    bf16x8 v0 = *(const bf16x8*)(xn + 8 * lane);
    unsigned u0 = *(const unsigned*)(xn + 512 + 2 * lane);
    float sA[8];
#pragma unroll
    for (int j = 0; j < 8; ++j){ sA[j] = bf2f_bits(v0[j]); accA[j] = sA[j]; }
    float sB0 = bf2f_bits((short)(u0 & 0xffff));
    float sB1 = bf2f_bits((short)(u0 >> 16));
    accB0 = sB0; accB1 = sB1;
    logits(sA, sB0, sB1, mA, mB);
    denA = 1.f; denB = 1.f;
  }

  // online update of one pair of edges given converted rows
  auto upd_pair = [&](const float* yA0, const float* yA1,
                      float yB00, float yB01, float yB10, float yB11){
    float lA0, lB0, lA1, lB1;
    logits(yA0, yB00, yB01, lA0, lB0);
    logits(yA1, yB10, yB11, lA1, lB1);
    {
      float m2 = fmaxf(mA, fmaxf(lA0, lA1));
      float sc = __expf(mA - m2);
      float p0 = __expf(lA0 - m2), p1 = __expf(lA1 - m2);
      denA = denA * sc + p0 + p1; mA = m2;
#pragma unroll
      for (int j = 0; j < 8; ++j) accA[j] = accA[j] * sc + p0 * yA0[j] + p1 * yA1[j];
    }
    {
      float m2 = fmaxf(mB, fmaxf(lB0, lB1));
      float sc = __expf(mB - m2);
      float p0 = __expf(lB0 - m2), p1 = __expf(lB1 - m2);
      denB = denB * sc + p0 + p1; mB = m2;
      accB0 = accB0 * sc + p0 * yB00 + p1 * yB10;
      accB1 = accB1 * sc + p0 * yB01 + p1 * yB11;
    }
  };

  int p = r0;
  for (; p + 3 < r1; p += 4){
    int s0i = srcg[p], s1i = srcg[p + 1], s2i = srcg[p + 2], s3i = srcg[p + 3];
    const bf16* q0 = xl + (size_t)s0i * HID;
    const bf16* q1 = xl + (size_t)s1i * HID;
    const bf16* q2 = xl + (size_t)s2i * HID;
    const bf16* q3 = xl + (size_t)s3i * HID;
    // issue all 8 row loads before any compute (hide gather latency)
    bf16x8 w0 = *(const bf16x8*)(q0 + 8 * lane);
    bf16x8 w1 = *(const bf16x8*)(q1 + 8 * lane);
    bf16x8 w2 = *(const bf16x8*)(q2 + 8 * lane);
    bf16x8 w3 = *(const bf16x8*)(q3 + 8 * lane);
    unsigned t0 = *(const unsigned*)(q0 + 512 + 2 * lane);
    unsigned t1 = *(const unsigned*)(q1 + 512 + 2 * lane);
    unsigned t2 = *(const unsigned*)(q2 + 512 + 2 * lane);
    unsigned t3 = *(const unsigned*)(q3 + 512 + 2 * lane);
    {
      float yA0[8], yA1[8];
#pragma unroll
      for (int j = 0; j < 8; ++j){ yA0[j] = bf2f_bits(w0[j]); yA1[j] = bf2f_bits(w1[j]); }
      upd_pair(yA0, yA1,
               bf2f_bits((short)(t0 & 0xffff)), bf2f_bits((short)(t0 >> 16)),
               bf2f_bits((short)(t1 & 0xffff)), bf2f_bits((short)(t1 >> 16)));
    }
    {
      float yA2[8], yA3[8];
#pragma unroll
      for (int j = 0; j < 8; ++j){ yA2[j] = bf2f_bits(w2[j]); yA3[j] = bf2f_bits(w3[j]); }
      upd_pair(yA2, yA3,
               bf2f_bits((short)(t2 & 0xffff)), bf2f_bits((short)(t2 >> 16)),
               bf2f_bits((short)(t3 & 0xffff)), bf2f_bits((short)(t3 >> 16)));
    }
  }
  for (; p + 1 < r1; p += 2){
    int s0i = srcg[p], s1i = srcg[p + 1];
    const bf16* q0 = xl + (size_t)s0i * HID;
    const bf16* q1 = xl + (size_t)s1i * HID;
    bf16x8 w0 = *(const bf16x8*)(q0 + 8 * lane);
    bf16x8 w1 = *(const bf16x8*)(q1 + 8 * lane);
    unsigned t0 = *(const unsigned*)(q0 + 512 + 2 * lane);
    unsigned t1 = *(const unsigned*)(q1 + 512 + 2 * lane);
    float yA0[8], yA1[8];
#pragma unroll
    for (int j = 0; j < 8; ++j){ yA0[j] = bf2f_bits(w0[j]); yA1[j] = bf2f_bits(w1[j]); }
    upd_pair(yA0, yA1,
             bf2f_bits((short)(t0 & 0xffff)), bf2f_bits((short)(t0 >> 16)),
             bf2f_bits((short)(t1 & 0xffff)), bf2f_bits((short)(t1 >> 16)));
  }
  if (p < r1){
    int si = srcg[p];
    const bf16* q0 = xl + (size_t)si * HID;
    bf16x8 w0 = *(const bf16x8*)(q0 + 8 * lane);
    unsigned t0 = *(const unsigned*)(q0 + 512 + 2 * lane);
    float yA0[8];
#pragma unroll
    for (int j = 0; j < 8; ++j) yA0[j] = bf2f_bits(w0[j]);
    float yB00 = bf2f_bits((short)(t0 & 0xffff)), yB01 = bf2f_bits((short)(t0 >> 16));
    float lA0, lB0;
    logits(yA0, yB00, yB01, lA0, lB0);
    {
      float m2 = fmaxf(mA, lA0);
      float sc = __expf(mA - m2);
      float p0 = __expf(lA0 - m2);
      denA = denA * sc + p0; mA = m2;
#pragma unroll
      for (int j = 0; j < 8; ++j) accA[j] = accA[j] * sc + p0 * yA0[j];
    }
    {
      float m2 = fmaxf(mB, lB0);
      float sc = __expf(mB - m2);
      float p0 = __expf(lB0 - m2);
      denB = denB * sc + p0; mB = m2;
      accB0 = accB0 * sc + p0 * yB00;
      accB1 = accB1 * sc + p0 * yB01;
    }
  }

  float invA = 1.f / denA, invB = 1.f / denB;
  float4 bA0 = *(const float4*)(bias + 8 * lane);
  float4 bA1 = *(const float4*)(bias + 8 * lane + 4);
  float2 bB  = *(const float2*)(bias + 512 + 2 * lane);
  float bAa[8] = {bA0.x, bA0.y, bA0.z, bA0.w, bA1.x, bA1.y, bA1.z, bA1.w};
  bf16x8 oA;
#pragma unroll
  for (int j = 0; j < 8; ++j){
    float v = accA[j] * invA + bAa[j];
    v = v > 0.f ? v : (__expf(v) - 1.f);              // ELU
    oA[j] = f2bf_bits(v);
  }
  float vb0 = accB0 * invB + bB.x; vb0 = vb0 > 0.f ? vb0 : (__expf(vb0) - 1.f);
  float vb1 = accB1 * invB + bB.y; vb1 = vb1 > 0.f ? vb1 : (__expf(vb1) - 1.f);
  bf16* hn = H + (size_t)n * HID;
  *(bf16x8*)(hn + 8 * lane) = oA;
  unsigned ob = (unsigned)(unsigned short)f2bf_bits(vb0) |
                ((unsigned)(unsigned short)f2bf_bits(vb1) << 16);
  *(unsigned*)(hn + 512 + 2 * lane) = ob;
}

// ---------------------------------------------------------------- GAT2 fused (1 head, full-wave logit reduce)
__global__ __launch_bounds__(256) void gat2_fused(const bf16* __restrict__ xl,
                                                  const bf16* __restrict__ xr,
                                                  const int* __restrict__ srcg,
                                                  const int* __restrict__ rowp,
                                                  const float* __restrict__ att,
                                                  const float* __restrict__ bias,
                                                  bf16* __restrict__ H){
  int n    = (blockIdx.x * 256 + threadIdx.x) >> 6;
  int lane = threadIdx.x & 63;
  if (n >= N_NODES) return;
  int r0 = rowp[n], r1 = rowp[n + 1];

  float4 aA0 = *(const float4*)(att + 8 * lane);
  float4 aA1 = *(const float4*)(att + 8 * lane + 4);
  float2 aBv = *(const float2*)(att + 512 + 2 * lane);
  float attA[8] = {aA0.x, aA0.y, aA0.z, aA0.w, aA1.x, aA1.y, aA1.z, aA1.w};
  float attB0 = aBv.x, attB1 = aBv.y;

  const bf16* xrn = xr + (size_t)n * HID;
  bf16x8 vr = *(const bf16x8*)(xrn + 8 * lane);
  unsigned ur = *(const unsigned*)(xrn + 512 + 2 * lane);
  float xrA[8];
#pragma unroll
  for (int j = 0; j < 8; ++j) xrA[j] = bf2f_bits(vr[j]);
  float xrB0 = bf2f_bits((short)(ur & 0xffff));
  float xrB1 = bf2f_bits((short)(ur >> 16));

  auto logit1 = [&](const float* xA, float xB0, float xB1)->float{
    float s0 = xB0 + xrB0; s0 *= (s0 > 0.f) ? 1.f : NEG_SLOPE;
    float s1 = xB1 + xrB1; s1 *= (s1 > 0.f) ? 1.f : NEG_SLOPE;
    float pa = attB0 * s0 + attB1 * s1;
#pragma unroll
    for (int j = 0; j < 8; ++j){
      float s = xA[j] + xrA[j];
      s *= (s > 0.f) ? 1.f : NEG_SLOPE;
      pa = fmaf(attA[j], s, pa);
    }
    pa += __shfl_xor(pa, 1);
    pa += __shfl_xor(pa, 2);
    pa += __shfl_xor(pa, 4);
    pa += __shfl_xor(pa, 8);
    pa += __shfl_xor(pa, 16);
    pa += __shfl_xor(pa, 32);
    return pa;
  };

  float accA[8], accB0, accB1, m, den;
  {
    const bf16* xn = xl + (size_t)n * HID;
    bf16x8 v0 = *(const bf16x8*)(xn + 8 * lane);
    unsigned u0 = *(const unsigned*)(xn + 512 + 2 * lane);
    float sA[8];
#pragma unroll
    for (int j = 0; j < 8; ++j){ sA[j] = bf2f_bits(v0[j]); accA[j] = sA[j]; }
    float sB0 = bf2f_bits((short)(u0 & 0xffff));
    float sB1 = bf2f_bits((short)(u0 >> 16));
    accB0 = sB0; accB1 = sB1;
    m = logit1(sA, sB0, sB1);
    den = 1.f;
  }

  auto upd_pair = [&](const float* yA0, const float* yA1,
                      float yB00, float yB01, float yB10, float yB11){
    float l0 = logit1(yA0, yB00, yB01);
    float l1 = logit1(yA1, yB10, yB11);
    float m2 = fmaxf(m, fmaxf(l0, l1));
    float sc = __expf(m - m2);
    float p0 = __expf(l0 - m2), p1 = __expf(l1 - m2);
    den = den * sc + p0 + p1; m = m2;
#pragma unroll
    for (int j = 0; j < 8; ++j) accA[j] = accA[j] * sc + p0 * yA0[j] + p1 * yA1[j];
    accB0 = accB0 * sc + p0 * yB00 + p1 * yB10;
    accB1 = accB1 * sc + p0 * yB01 + p1 * yB11;
  };

  int p = r0;
  for (; p + 3 < r1; p += 4){
    int s0i = srcg[p], s1i = srcg[p + 1], s2i = srcg[p + 2], s3i = srcg[p + 3];
    const bf16* q0 = xl + (size_t)s0i * HID;
    const bf16* q1 = xl + (size_t)s1i * HID;
    const bf16* q2 = xl + (size_t)s2i * HID;
    const bf16* q3 = xl + (size_t)s3i * HID;
    bf16x8 w0 = *(const bf16x8*)(q0 + 8 * lane);
    bf16x8 w1 = *(const bf16x8*)(q1 + 8 * lane);
    bf16x8 w2 = *(const bf16x8*)(q2 + 8 * lane);
    bf16x8 w3 = *(const bf16x8*)(q3 + 8 * lane);
    unsigned t0 = *(const unsigned*)(q0 + 512 + 2 * lane);
    unsigned t1 = *(const unsigned*)(q1 + 512 + 2 * lane);
    unsigned t2 = *(const unsigned*)(q2 + 512 + 2 * lane);
    unsigned t3 = *(const unsigned*)(q3 + 512 + 2 * lane);
    {
      float yA0[8], yA1[8];
#pragma unroll
      for (int j = 0; j < 8; ++j){ yA0[j] = bf2f_bits(w0[j]); yA1[j] = bf2f_bits(w1[j]); }
      upd_pair(yA0, yA1,
               bf2f_bits((short)(t0 & 0xffff)), bf2f_bits((short)(t0 >> 16)),
               bf2f_bits((short)(t1 & 0xffff)), bf2f_bits((short)(t1 >> 16)));
    }
    {
      float yA2[8], yA3[8];
#pragma unroll
      for (int j = 0; j < 8; ++j){ yA2[j] = bf2f_bits(w2[j]); yA3[j] = bf2f_bits(w3[j]); }
      upd_pair(yA2, yA3,
               bf2f_bits((short)(t2 & 0xffff)), bf2f_bits((short)(t2 >> 16)),
               bf2f_bits((short)(t3 & 0xffff)), bf2f_bits((short)(t3 >> 16)));
    }
  }
  for (; p + 1 < r1; p += 2){
    int s0i = srcg[p], s1i = srcg[p + 1];
    const bf16* q0 = xl + (size_t)s0i * HID;
    const bf16* q1 = xl + (size_t)s1i * HID;
    bf16x8 w0 = *(const bf16x8*)(q0 + 8 * lane);
    bf16x8 w1 = *(const bf16x8*)(q1 + 8 * lane);
    unsigned t0 = *(const unsigned*)(q0 + 512 + 2 * lane);
    unsigned t1 = *(const unsigned*)(q1 + 512 + 2 * lane);
    float yA0[8], yA1[8];
#pragma unroll
    for (int j = 0; j < 8; ++j){ yA0[j] = bf2f_bits(w0[j]); yA1[j] = bf2f_bits(w1[j]); }
    upd_pair(yA0, yA1,
             bf2f_bits((short)(t0 & 0xffff)), bf2f_bits((short)(t0 >> 16)),
             bf2f_bits((short)(t1 & 0xffff)), bf2f_bits((short)(t1 >> 16)));
  }
  if (p < r1){
    int si = srcg[p];
    const bf16* q0 = xl + (size_t)si * HID;
    bf16x8 w0 = *(const bf16x8*)(q0 + 8 * lane);
    unsigned t0 = *(const unsigned*)(q0 + 512 + 2 * lane);
    float yA0[8];
#pragma unroll
    for (int j = 0; j < 8; ++j) yA0[j] = bf2f_bits(w0[j]);
    float yB00 = bf2f_bits((short)(t0 & 0xffff)), yB01 = bf2f_bits((short)(t0 >> 16));
    float l0 = logit1(yA0, yB00, yB01);
    float m2 = fmaxf(m, l0);
    float sc = __expf(m - m2);
    float p0 = __expf(l0 - m2);
    den = den * sc + p0; m = m2;
#pragma unroll
    for (int j = 0; j < 8; ++j) accA[j] = accA[j] * sc + p0 * yA0[j];
    accB0 = accB0 * sc + p0 * yB00;
    accB1 = accB1 * sc + p0 * yB01;
  }

  float inv = 1.f / den;
  float4 bA0 = *(const float4*)(bias + 8 * lane);
  float4 bA1 = *(const float4*)(bias + 8 * lane + 4);
  float2 bB  = *(const float2*)(bias + 512 + 2 * lane);
  float bAa[8] = {bA0.x, bA0.y, bA0.z, bA0.w, bA1.x, bA1.y, bA1.z, bA1.w};
  bf16x8 oA;
#pragma unroll
  for (int j = 0; j < 8; ++j) oA[j] = f2bf_bits(accA[j] * inv + bAa[j]);
  bf16* hn = H + (size_t)n * HID;
  *(bf16x8*)(hn + 8 * lane) = oA;
  unsigned ob = (unsigned)(unsigned short)f2bf_bits(accB0 * inv + bB.x) |
                ((unsigned)(unsigned short)f2bf_bits(accB1 * inv + bB.y) << 16);
  *(unsigned*)(hn + 512 + 2 * lane) = ob;
}

// ---------------------------------------------------------------- GCN gather: bias+ReLU -> bf16 h3 (4-wide issue)
__global__ __launch_bounds__(256) void gcn_gather(const bf16* __restrict__ xw,
                                                  const int* __restrict__ srcg,
                                                  const int* __restrict__ rowp,
                                                  const float* __restrict__ dinv,
                                                  const float* __restrict__ bg,
                                                  bf16* __restrict__ h3){
  int n    = (blockIdx.x * 256 + threadIdx.x) >> 6;
  int lane = threadIdx.x & 63;
  if (n >= N_NODES) return;
  int r0 = rowp[n], r1 = rowp[n + 1];

  float dn = dinv[n];
  float accA[8], accB[2];
  {
    float w = dn * dn;
    const bf16* xn = xw + (size_t)n * HID;
    bf16x8 va = *(const bf16x8*)(xn + 8 * lane);
    unsigned vb = *(const unsigned*)(xn + 512 + 2 * lane);
#pragma unroll
    for (int j = 0; j < 8; ++j) accA[j] = w * bf2f_bits(va[j]);
    accB[0] = w * bf2f_bits((short)(vb & 0xffff));
    accB[1] = w * bf2f_bits((short)(vb >> 16));
  }
  int p = r0;
  for (; p + 3 < r1; p += 4){
    int s0 = srcg[p], s1 = srcg[p + 1], s2 = srcg[p + 2], s3 = srcg[p + 3];
    const bf16* xs0 = xw + (size_t)s0 * HID;
    const bf16* xs1 = xw + (size_t)s1 * HID;
    const bf16* xs2 = xw + (size_t)s2 * HID;
    const bf16* xs3 = xw + (size_t)s3 * HID;
    // issue all loads before compute
    float w0 = dinv[s0] * dn, w1 = dinv[s1] * dn, w2 = dinv[s2] * dn, w3 = dinv[s3] * dn;
    bf16x8 va0 = *(const bf16x8*)(xs0 + 8 * lane);
    bf16x8 va1 = *(const bf16x8*)(xs1 + 8 * lane);
    bf16x8 va2 = *(const bf16x8*)(xs2 + 8 * lane);
    bf16x8 va3 = *(const bf16x8*)(xs3 + 8 * lane);
    unsigned vb0 = *(const unsigned*)(xs0 + 512 + 2 * lane);
    unsigned vb1 = *(const unsigned*)(xs1 + 512 + 2 * lane);
    unsigned vb2 = *(const unsigned*)(xs2 + 512 + 2 * lane);
    unsigned vb3 = *(const unsigned*)(xs3 + 512 + 2 * lane);
#pragma unroll
    for (int j = 0; j < 8; ++j)
      accA[j] += w0 * bf2f_bits(va0[j]) + w1 * bf2f_bits(va1[j])
               + w2 * bf2f_bits(va2[j]) + w3 * bf2f_bits(va3[j]);
    accB[0] += w0 * bf2f_bits((short)(vb0 & 0xffff)) + w1 * bf2f_bits((short)(vb1 & 0xffff))
             + w2 * bf2f_bits((short)(vb2 & 0xffff)) + w3 * bf2f_bits((short)(vb3 & 0xffff));
    accB[1] += w0 * bf2f_bits((short)(vb0 >> 16))    + w1 * bf2f_bits((short)(vb1 >> 16))
             + w2 * bf2f_bits((short)(vb2 >> 16))    + w3 * bf2f_bits((short)(vb3 >> 16));
  }
  for (; p + 1 < r1; p += 2){
    int s0 = srcg[p], s1 = srcg[p + 1];
    float w0 = dinv[s0] * dn, w1 = dinv[s1] * dn;
    const bf16* xs0 = xw + (size_t)s0 * HID;
    const bf16* xs1 = xw + (size_t)s1 * HID;
    bf16x8 va0 = *(const bf16x8*)(xs0 + 8 * lane);
    bf16x8 va1 = *(const bf16x8*)(xs1 + 8 * lane);
    unsigned vb0 = *(const unsigned*)(xs0 + 512 + 2 * lane);
    unsigned vb1 = *(const unsigned*)(xs1 + 512 + 2 * lane);
#pragma unroll
    for (int j = 0; j < 8; ++j) accA[j] += w0 * bf2f_bits(va0[j]) + w1 * bf2f_bits(va1[j]);
    accB[0] += w0 * bf2f_bits((short)(vb0 & 0xffff)) + w1 * bf2f_bits((short)(vb1 & 0xffff));
    accB[1] += w0 * bf2f_bits((short)(vb0 >> 16))    + w1 * bf2f_bits((short)(vb1 >> 16));
  }
  if (p < r1){
    int s = srcg[p];
    float w = dinv[s] * dn;
    const bf16* xs = xw + (size_t)s * HID;
    bf16x8 va = *(const bf16x8*)(xs + 8 * lane);
    unsigned vb = *(const unsigned*)(xs + 512 + 2 * lane);
#pragma unroll
    for (int j = 0; j < 8; ++j) accA[j] += w * bf2f_bits(va[j]);
    accB[0] += w * bf2f_bits((short)(vb & 0xffff));
    accB[1] += w * bf2f_bits((short)(vb >> 16));
  }
  float4 bA0 = *(const float4*)(bg + 8 * lane);
  float4 bA1 = *(const float4*)(bg + 8 * lane + 4);
  float2 bB  = *(const float2*)(bg + 512 + 2 * lane);
  float bAa[8] = {bA0.x, bA0.y, bA0.z, bA0.w, bA1.x, bA1.y, bA1.z, bA1.w};
  bf16x8 oA;
#pragma unroll
  for (int j = 0; j < 8; ++j) oA[j] = f2bf_bits(fmaxf(accA[j] + bAa[j], 0.f));
  bf16* hn = h3 + (size_t)n * HID;
  *(bf16x8*)(hn + 8 * lane) = oA;
  unsigned ob = (unsigned)(unsigned short)f2bf_bits(fmaxf(accB[0] + bB.x, 0.f)) |
                ((unsigned)(unsigned short)f2bf_bits(fmaxf(accB[1] + bB.y, 0.f)) << 16);
  *(unsigned*)(hn + 512 + 2 * lane) = ob;
}

// ---------------------------------------------------------------- per-graph pooling (batch is sorted)
__global__ __launch_bounds__(256) void graph_bounds(const int* __restrict__ batch,
                                                    int* __restrict__ gstart){
  int n = blockIdx.x * 256 + threadIdx.x;
  if (n >= N_NODES) return;
  int b = clampi(batch[n], N_GRAPHS);
  if (n == 0){
    for (int g = 0; g <= b; ++g) gstart[g] = 0;
  } else {
    int bp = clampi(batch[n - 1], N_GRAPHS);
    for (int g = bp + 1; g <= b; ++g) gstart[g] = n;
  }
  if (n == N_NODES - 1){
    for (int g = b + 1; g <= N_GRAPHS; ++g) gstart[g] = N_NODES;
  }
}

// 320 threads: lane t owns channels 2t, 2t+1 (4 B/lane loads)
__global__ __launch_bounds__(320) void pool_graph(const bf16* __restrict__ h3,
                                                  const int* __restrict__ gstart,
                                                  float* __restrict__ out){
  int g = blockIdx.x;
  int c2 = threadIdx.x;
  int n0 = gstart[g], n1 = gstart[g + 1];
  float mx0 = 0.f, mx1 = 0.f, sm0 = 0.f, sm1 = 0.f;   // h3 >= 0 post-ReLU
  for (int n = n0; n < n1; ++n){
    unsigned v = *(const unsigned*)(h3 + (size_t)n * HID + 2 * c2);
    float a = bf2f_bits((short)(v & 0xffff));
    float b = bf2f_bits((short)(v >> 16));
    mx0 = fmaxf(mx0, a); sm0 += a;
    mx1 = fmaxf(mx1, b); sm1 += b;
  }
  float inv = (n1 > n0) ? 1.f / (float)(n1 - n0) : 0.f;
  float* og = out + (size_t)g * 2 * HID;
  og[2 * c2]             = mx0;
  og[2 * c2 + 1]         = mx1;
  og[HID + 2 * c2]       = sm0 * inv;
  og[HID + 2 * c2 + 1]   = sm1 * inv;
}

// ---------------------------------------------------------------- launch
extern "C" void kernel_launch(void* const* d_in, const int* in_sizes, int n_in,
                              void* d_out, int out_size, void* d_ws, size_t ws_size,
                              hipStream_t stream){
  const float* x     = (const float*)d_in[0];
  const int*   ei    = (const int*)d_in[1];
  const int*   batch = (const int*)d_in[2];
  const float* Wl1 = (const float*)d_in[3];
  const float* Wr1 = (const float*)d_in[4];
  const float* a1  = (const float*)d_in[5];
  const float* b1  = (const float*)d_in[6];
  const float* Wl2 = (const float*)d_in[7];
  const float* Wr2 = (const float*)d_in[8];
  const float* a2  = (const float*)d_in[9];
  const float* b2  = (const float*)d_in[10];
  const float* Wg  = (const float*)d_in[11];
  const float* bg  = (const float*)d_in[12];
  const int* esrc = ei;
  const int* edst = ei + N_EDGES;

  // ---- workspace layout ----
  char* ws = (char*)d_ws;
  size_t off = 0;
  auto take = [&](size_t bytes)->char*{
    char* p = ws + off; off = (off + bytes + 255) & ~(size_t)255; return p;
  };
  bf16*     X1   = (bf16*)    take((size_t)N_NODES * HID * 2);
  bf16*     X2   = (bf16*)    take((size_t)N_NODES * HID * 2);
  bf16*     H    = (bf16*)    take((size_t)N_NODES * HID * 2);
  bf16*     XB   = (bf16*)    take((size_t)N_NODES * K1P * 2);
  // WT1l|WT1r contiguous (one 1280xK1P matrix); WT2l|WT2r|WTg contiguous.
  bf16*     WT1l = (bf16*)    take((size_t)HID * K1P * 2);
  bf16*     WT1r = (bf16*)    take((size_t)HID * K1P * 2);
  bf16*     WT2l = (bf16*)    take((size_t)HID * HID * 2);
  bf16*     WT2r = (bf16*)    take((size_t)HID * HID * 2);
  bf16*     WTg  = (bf16*)    take((size_t)HID * HID * 2);
  int*      DEGI = (int*)     take((size_t)N_NODES * 4);
  int*      ROWP = (int*)     take((size_t)(N_NODES + 1) * 4);
  int*      CURS = (int*)     take((size_t)N_NODES * 4);
  int*      SRCG = (int*)     take((size_t)N_EDGES * 4);
  int*      DSTG = (int*)     take((size_t)N_EDGES * 4);
  float*    DINV = (float*)   take((size_t)N_NODES * 4);
  int*      GST  = (int*)     take((size_t)(N_GRAPHS + 1) * 4);
  int*      BSUM = (int*)     take((size_t)SCB * 4);
  (void)WT1r; (void)WT2r; (void)DSTG;

  dim3 blk(256);
  auto fill = [&](void* p, unsigned v, int n){
    fill_u32<<<dim3((n + 255) / 256), blk, 0, stream>>>((unsigned*)p, v, n);
  };
  const int MB8     = ((N_NODES + BM - 1) / BM + 7) / 8;   // 128-row strips per XCD (49)
  const int nblocks = (N_NODES * 64 + 255) / 256;
  const int reblk   = (N_EDGES + 255) / 256;

  // ---- prep + CSR ----
  conv_x<<<(N_NODES * K1P + 255) / 256, blk, 0, stream>>>(x, XB);
  conv_wT2<<<(2 * HID * K1P + 255) / 256, blk, 0, stream>>>(Wl1, Wr1, WT1l, IN_DIM, HID, K1P);
  conv_wT3t<<<dim3(HID / 32, HID / 32, 3), blk, 0, stream>>>(Wl2, Wr2, Wg, WT2l);
  fill(DEGI, 0u, N_NODES);
  count_deg<<<reblk, blk, 0, stream>>>(edst, DEGI);
  scan_blk<<<dim3(SCB), blk, 0, stream>>>(DEGI, ROWP, DINV, BSUM);
  scan_top<<<dim3(1), blk, 0, stream>>>(BSUM, ROWP);
  scan_add<<<dim3(SCB), blk, 0, stream>>>(BSUM, ROWP, CURS);
  bucket_edges<<<reblk, blk, 0, stream>>>(esrc, edst, CURS, SRCG, DSTG);
  graph_bounds<<<(N_NODES + 255) / 256, blk, 0, stream>>>(batch, GST);

  // ---- GATv2 layer 1 (merged Wl|Wr GEMM, N=1280; fused logits+agg) ----
  mfma_gemm<<<dim3(8 * MB8 * 10), blk, 0, stream>>>(XB, WT1l, X1, X2, N_NODES, K1P, 10);
  gat1_fused<<<nblocks, blk, 0, stream>>>(X1, X2, SRCG, ROWP, a1, b1, H);

  // ---- GATv2 layer 2 (merged Wl|Wr GEMM, N=1280; fused logits+agg) ----
  mfma_gemm<<<dim3(8 * MB8 * 10), blk, 0, stream>>>(H, WT2l, X1, X2, N_NODES, HID, 10);
  gat2_fused<<<nblocks, blk, 0, stream>>>(X1, X2, SRCG, ROWP, a2, b2, H);

  // ---- GCN + pooling ----
  mfma_gemm<<<dim3(8 * MB8 * 5), blk, 0, stream>>>(H, WTg, X1, X1, N_NODES, HID, 5);
  gcn_gather<<<nblocks, blk, 0, stream>>>(X1, SRCG, ROWP, DINV, bg, X2);
  pool_graph<<<dim3(N_GRAPHS), dim3(320), 0, stream>>>(X2, GST, (float*)d_out);
}